// Round 18
// baseline (486.126 us; speedup 1.0000x reference)
//
#include <hip/hip_runtime.h>
#include <math.h>

#define Bn  8
#define SQn 2048
#define SKn 2048
#define Hn  256
#define NHn 4
#define HDn 64
#define SCALE2 0.1803368801111f   /* 0.125 * log2(e) */

typedef __attribute__((ext_vector_type(4))) float f32x4;
typedef __attribute__((ext_vector_type(4))) unsigned int u32x4;
typedef __attribute__((ext_vector_type(8))) short short8;
typedef unsigned short ushort_t;
typedef unsigned long long ull_t;

__device__ __forceinline__ unsigned short f2bf(float f) {
  unsigned u = __builtin_bit_cast(unsigned, f);
  u += 0x7fffu + ((u >> 16) & 1u);
  return (unsigned short)(u >> 16);
}

__device__ __forceinline__ float fexp2(float x) {
  return __builtin_amdgcn_exp2f(x);
}

__device__ __forceinline__ float bf2f(unsigned short v) {
  unsigned u = (unsigned)v << 16;
  return __builtin_bit_cast(float, u);
}

__device__ __forceinline__ short8 load8f(const float* p) {
  float4 v0 = *(const float4*)p;
  float4 v1 = *(const float4*)(p + 4);
  short8 r;
  r[0] = (short)f2bf(v0.x); r[1] = (short)f2bf(v0.y);
  r[2] = (short)f2bf(v0.z); r[3] = (short)f2bf(v0.w);
  r[4] = (short)f2bf(v1.x); r[5] = (short)f2bf(v1.y);
  r[6] = (short)f2bf(v1.z); r[7] = (short)f2bf(v1.w);
  return r;
}

__device__ __forceinline__ f32x4 mfma16(short8 a, short8 b, f32x4 c) {
  return __builtin_amdgcn_mfma_f32_16x16x32_bf16(a, b, c, 0, 0, 0);
}

// -------- merged: Q/K/V projection GEMMs + mask->bitwords in ONE kernel.
// Blocks [0,1024): maskbits (HBM-streaming, 4 independent ballot chains).
// Blocks [1024,4096): the 3 projection GEMMs (MFMA/latency-bound).
// The two populations are independent and occupy complementary pipes, so
// the mask stream hides under the projections instead of serializing.
__global__ __launch_bounds__(256) void projmask_kernel(
    const void* __restrict__ maskp,
    const float* __restrict__ Xq, const float* __restrict__ Xk,
    const float* __restrict__ Xv,
    const float* __restrict__ Wqp, const float* __restrict__ bqp,
    const float* __restrict__ Wkp, const float* __restrict__ bkp,
    const float* __restrict__ Wvp, const float* __restrict__ bvp,
    ushort_t* __restrict__ Qb, ushort_t* __restrict__ Kb,
    ushort_t* __restrict__ Vt, ull_t* __restrict__ mout)
{
  const int bid = blockIdx.x;
  if (bid < 1024) {
    // ---- maskbits: 4096 waves stream the 2048x2048x8 mask
    const int l = threadIdx.x & 63;
    const unsigned probe = ((const unsigned*)maskp)[l];
    const int isbyte = __any(probe > 1u);
    const int gwave = (bid * 256 + threadIdx.x) >> 6;
    const int nwaves = 1024 * 4;
    const long long total4 = (long long)Bn * SQn * (SKn / 256);
    if (isbyte) {
      for (long long w = gwave; w < total4; w += nwaves) {
        const unsigned char* mp = (const unsigned char*)maskp + w * 256;
        bool n0 = mp[l] != 0,        n1 = mp[64 + l] != 0;
        bool n2 = mp[128 + l] != 0,  n3 = mp[192 + l] != 0;
        ull_t b0 = __ballot(n0), b1 = __ballot(n1);
        ull_t b2 = __ballot(n2), b3 = __ballot(n3);
        if (l == 0) {
          mout[w * 4] = b0; mout[w * 4 + 1] = b1;
          mout[w * 4 + 2] = b2; mout[w * 4 + 3] = b3;
        }
      }
    } else {
      for (long long w = gwave; w < total4; w += nwaves) {
        const int* mp = (const int*)maskp + w * 256;
        bool n0 = mp[l] != 0,        n1 = mp[64 + l] != 0;
        bool n2 = mp[128 + l] != 0,  n3 = mp[192 + l] != 0;
        ull_t b0 = __ballot(n0), b1 = __ballot(n1);
        ull_t b2 = __ballot(n2), b3 = __ballot(n3);
        if (l == 0) {
          mout[w * 4] = b0; mout[w * 4 + 1] = b1;
          mout[w * 4 + 2] = b2; mout[w * 4 + 3] = b3;
        }
      }
    }
    return;
  }

  // ---- projection GEMMs (R14-proven body: f32 X and W, in-kernel cvt)
  const int pid = bid - 1024;                 // [0, 3072)
  const int which = pid >> 10;                // 0:Q 1:K 2:V
  const int rem = pid & 1023;
  const int m0 = (rem >> 2) * 64;
  const int n0 = (rem & 3) * 64;

  const float* X = which == 0 ? Xq : which == 1 ? Xk : Xv;
  const float* W = which == 0 ? Wqp : which == 1 ? Wkp : Wvp;
  const float* bias = which == 0 ? bqp : which == 1 ? bkp : bvp;
  ushort_t* Y = which == 0 ? Qb : which == 1 ? Kb : Vt;
  const int vtrans = (which == 2);

  const int wv = threadIdx.x >> 6;
  const int l  = threadIdx.x & 63;
  const int lr = l & 15, lg = l >> 4;
  const int mrow = m0 + wv * 16 + lr;

  f32x4 acc[4];
  #pragma unroll
  for (int t = 0; t < 4; ++t) acc[t] = (f32x4){0.f, 0.f, 0.f, 0.f};

  const float* ap = X + (size_t)mrow * Hn + lg * 8;
  for (int k0 = 0; k0 < Hn; k0 += 32) {
    short8 a = load8f(ap + k0);
    #pragma unroll
    for (int t = 0; t < 4; ++t) {
      short8 bb = load8f(W + (size_t)(n0 + t * 16 + lr) * Hn + k0 + lg * 8);
      acc[t] = mfma16(a, bb, acc[t]);
    }
  }

  #pragma unroll
  for (int t = 0; t < 4; ++t) {
    const int n = n0 + t * 16 + lr;
    const float bv = bias[n];
    const int h = n >> 6, d = n & 63;
    if (!vtrans) {
      #pragma unroll
      for (int r = 0; r < 4; ++r) {
        const int m = m0 + wv * 16 + lg * 4 + r;
        const int bb = m >> 11, s = m & 2047;
        size_t idx = (((size_t)bb * NHn + h) * SQn + s) * HDn + d;
        Y[idx] = f2bf(acc[t][r] + bv);
      }
    } else {
      const int m = m0 + wv * 16 + lg * 4;
      const int bb = m >> 11, s = m & 2047;
      ushort4 pk;
      pk.x = f2bf(acc[t][0] + bv); pk.y = f2bf(acc[t][1] + bv);
      pk.z = f2bf(acc[t][2] + bv); pk.w = f2bf(acc[t][3] + bv);
      size_t idx = (((size_t)bb * NHn + h) * HDn + d) * (size_t)SKn + s;
      *(ushort4*)(Y + idx) = pk;
    }
  }
}

// ------------------------------------------- single-pass fused attention
// EXACT R9/R14 kernel (proven optimum of this structure: 325 us, spill-free,
// absmax 6.1e-5, occupancy 44%). Register bracket (R10/R11/R15): the ~110-reg
// live set needs the 128-reg budget; lower budgets spill (R10 -1.3GB,
// R11 -205MB); off-loading p-hat to memory (R15) costs +800MB (+125us);
// scheduling hints (R17 setprio/V-hoist/mask-preload) are null.
__global__ __launch_bounds__(512)
__attribute__((amdgpu_waves_per_eu(4, 4)))
void fused_attn_kernel(
    const ushort_t* __restrict__ Qb, const ushort_t* __restrict__ Kb,
    const ushort_t* __restrict__ Vt, const unsigned* __restrict__ maskbits,
    float* __restrict__ attn_out, ushort_t* __restrict__ Ob)
{
  __shared__ float red[8][16];
  __shared__ float Opart[8][16][66];  // +2 pad kills bank conflicts

  const int bid = blockIdx.x;
  const int rt = (bid & 7) * 512 + (bid >> 3);  // XCD-chunked bijection
  const int wv = threadIdx.x >> 6;
  const int l  = threadIdx.x & 63;
  const int lr = l & 15, lg = l >> 4;
  const int bh = rt >> 7;
  const int q0 = (rt & 127) << 4;
  const int b  = bh >> 2, h = bh & 3;
  const int colbase = wv * 256;

  const ushort_t* Qh = Qb + (size_t)bh * SQn * HDn;
  const ushort_t* Kh = Kb + (size_t)bh * SKn * HDn;
  const ushort_t* Vh = Vt + (size_t)bh * HDn * SKn;

  short8 qa0 = *(const short8*)(Qh + (q0 + lr) * HDn + lg * 8);
  short8 qa1 = *(const short8*)(Qh + (q0 + lr) * HDn + 32 + lg * 8);

  const int krA = (lr >> 2) * 8 + (lr & 3);
  const unsigned* mrow = maskbits + ((size_t)b * SQn + q0 + lr) * (SKn / 32) + wv * 8;
  const int bsh = lg * 8;

  // ---- Phase A: QK^T once; packed p-hat + row-sum + unnormalized PV
  short8 pf8[8];
  float lsum = 0.f;
  f32x4 oacc[4];
  #pragma unroll
  for (int dt = 0; dt < 4; ++dt) oacc[dt] = (f32x4){0.f, 0.f, 0.f, 0.f};

  u32x4 mw = *(const u32x4*)mrow;   // second half loaded at s8==4
  #pragma unroll
  for (int s8 = 0; s8 < 8; ++s8) {
    if (s8 == 4) mw = *(const u32x4*)(mrow + 4);
    const int c = colbase + s8 * 32;
    const ushort_t* kp = Kh + (size_t)(c + krA) * HDn + lg * 8;
    short8 ka0 = *(const short8*)(kp);
    short8 ka1 = *(const short8*)(kp + 32);
    short8 kb0 = *(const short8*)(kp + 4 * HDn);
    short8 kb1 = *(const short8*)(kp + 4 * HDn + 32);
    f32x4 za = (f32x4){0.f, 0.f, 0.f, 0.f}, zb = (f32x4){0.f, 0.f, 0.f, 0.f};
    za = mfma16(ka0, qa0, za); za = mfma16(ka1, qa1, za);
    zb = mfma16(kb0, qa0, zb); zb = mfma16(kb1, qa1, zb);

    // V loads issued here: K regs dead, exp/pack VALU below hides latency
    const ushort_t* vp = Vh + (size_t)lr * SKn + c + lg * 8;
    short8 vb0 = *(const short8*)(vp);
    short8 vb1 = *(const short8*)(vp + 16 * SKn);
    short8 vb2 = *(const short8*)(vp + 32 * SKn);
    short8 vb3 = *(const short8*)(vp + 48 * SKn);

    const unsigned bits = (mw[s8 & 3] >> bsh) & 0xFFu;
    short8 pf;
    #pragma unroll
    for (int j = 0; j < 4; ++j) {
      float pa = ((bits >> j) & 1) ? fexp2(za[j] * SCALE2) : 0.f;
      float pb = ((bits >> (4 + j)) & 1) ? fexp2(zb[j] * SCALE2) : 0.f;
      lsum += pa + pb;
      pf[j] = (short)f2bf(pa);
      pf[4 + j] = (short)f2bf(pb);
    }
    pf8[s8] = pf;
    oacc[0] = mfma16(pf, vb0, oacc[0]);
    oacc[1] = mfma16(pf, vb1, oacc[1]);
    oacc[2] = mfma16(pf, vb2, oacc[2]);
    oacc[3] = mfma16(pf, vb3, oacc[3]);
  }

  // row-sum across the 4 lane-groups sharing row lr; stash partial O
  lsum += __shfl_xor(lsum, 16);
  lsum += __shfl_xor(lsum, 32);
  if (l < 16) red[wv][lr] = lsum;
  #pragma unroll
  for (int dt = 0; dt < 4; ++dt)
    #pragma unroll
    for (int r = 0; r < 4; ++r)
      Opart[wv][lg * 4 + r][dt * 16 + lr] = oacc[dt][r];
  __syncthreads();

  float gsum = 0.f;
  #pragma unroll
  for (int ww = 0; ww < 8; ++ww) gsum += red[ww][lr];
  const bool rowempty = (gsum == 0.f);   // fully-masked row (exact)
  const float rinv = rowempty ? 0.f : 1.f / gsum;

  // ---- Phase B: attn = bf16(p-hat) * rinv, plain cached stores
  float* arow = attn_out + ((size_t)bh * SQn + q0 + lr) * (size_t)SKn;
  #pragma unroll
  for (int s8 = 0; s8 < 8; ++s8) {
    const int c = colbase + s8 * 32;
    float av[8];
    #pragma unroll
    for (int j = 0; j < 8; ++j)
      av[j] = bf2f((unsigned short)pf8[s8][j]) * rinv;
    if (rowempty && s8 == 0 && wv == 0 && lg == 0) av[0] = 1.f;  // one-hot key 0
    *(f32x4*)(arow + c + lg * 8)     = (f32x4){av[0], av[1], av[2], av[3]};
    *(f32x4*)(arow + c + lg * 8 + 4) = (f32x4){av[4], av[5], av[6], av[7]};
  }

  // ---- epilogue: cross-wave O reduce, scale by 1/gsum per row
  #pragma unroll
  for (int e = threadIdx.x; e < 1024; e += 512) {
    const int row = e >> 6, d = e & 63;
    float gs = 0.f;
    #pragma unroll
    for (int ww = 0; ww < 8; ++ww) gs += red[ww][row];
    float s = 0.f;
    #pragma unroll
    for (int ww = 0; ww < 8; ++ww) s += Opart[ww][row][d];
    float val;
    if (gs == 0.f) {  // fully-masked row: attn=one-hot(key0) -> O=V[:,0]
      val = bf2f(Vh[(size_t)d * SKn]);
    } else {
      val = s / gs;
    }
    Ob[((size_t)b * SQn + q0 + row) * Hn + h * HDn + d] = f2bf(val);
  }
}

// ------------------------------------------------ output projection
__global__ __launch_bounds__(256) void oproj_kernel(
    const unsigned short* __restrict__ A, const float* __restrict__ W,
    const float* __restrict__ bias, float* __restrict__ out)
{
  const int m0 = blockIdx.x * 64;
  const int n0 = blockIdx.y * 64;
  const int wv = threadIdx.x >> 6;
  const int l  = threadIdx.x & 63;
  const int lr = l & 15, lg = l >> 4;
  const int mrow = m0 + wv * 16 + lr;

  f32x4 acc[4];
  #pragma unroll
  for (int t = 0; t < 4; ++t) acc[t] = (f32x4){0.f, 0.f, 0.f, 0.f};

  for (int k0 = 0; k0 < Hn; k0 += 32) {
    short8 a = *(const short8*)(A + (size_t)mrow * Hn + k0 + lg * 8);
    #pragma unroll
    for (int t = 0; t < 4; ++t) {
      short8 bb = load8f(W + (size_t)(n0 + t * 16 + lr) * Hn + k0 + lg * 8);
      acc[t] = mfma16(a, bb, acc[t]);
    }
  }
  #pragma unroll
  for (int t = 0; t < 4; ++t) {
    const int n = n0 + t * 16 + lr;
    const float bv = bias[n];
    #pragma unroll
    for (int r = 0; r < 4; ++r) {
      const int m = m0 + wv * 16 + lg * 4 + r;
      out[(size_t)m * Hn + n] = acc[t][r] + bv;
    }
  }
}

extern "C" void kernel_launch(void* const* d_in, const int* in_sizes, int n_in,
                              void* d_out, int out_size, void* d_ws, size_t ws_size,
                              hipStream_t stream) {
  const float* query = (const float*)d_in[0];
  const float* key_  = (const float*)d_in[1];
  const float* value = (const float*)d_in[2];
  const void*  mask  = d_in[3];
  const float* Wq = (const float*)d_in[4];
  const float* bq = (const float*)d_in[5];
  const float* Wk = (const float*)d_in[6];
  const float* bk = (const float*)d_in[7];
  const float* Wv = (const float*)d_in[8];
  const float* bv = (const float*)d_in[9];
  const float* Wo = (const float*)d_in[10];
  const float* bo = (const float*)d_in[11];

  float* out  = (float*)d_out;
  float* attn = out + (size_t)Bn * SQn * Hn;

  char* ws = (char*)d_ws;
  unsigned short* Qb = (unsigned short*)ws;
  unsigned short* Kb = Qb + (size_t)Bn * SQn * Hn;
  unsigned short* Vt = Kb + (size_t)Bn * SKn * Hn;
  unsigned short* Ob = Vt + (size_t)Bn * SKn * Hn;
  unsigned* mbits = (unsigned*)(Ob + (size_t)Bn * SQn * Hn);  // 4 MiB bitmask

  projmask_kernel<<<4096, 256, 0, stream>>>(
      mask, query, key_, value, Wq, bq, Wk, bk, Wv, bv, Qb, Kb, Vt,
      (ull_t*)mbits);
  fused_attn_kernel<<<4096, 512, 0, stream>>>(Qb, Kb, Vt, mbits, attn, Ob);
  oproj_kernel<<<dim3(256, 4), 256, 0, stream>>>(Ob, Wo, bo, out);
}

// Round 19
// 482.120 us; speedup vs baseline: 1.0083x; 1.0083x over previous
//
#include <hip/hip_runtime.h>
#include <math.h>

#define Bn  8
#define SQn 2048
#define SKn 2048
#define Hn  256
#define NHn 4
#define HDn 64
#define SCALE2 0.1803368801111f   /* 0.125 * log2(e) */

typedef __attribute__((ext_vector_type(4))) float f32x4;
typedef __attribute__((ext_vector_type(4))) unsigned int u32x4;
typedef __attribute__((ext_vector_type(8))) short short8;
typedef unsigned short ushort_t;
typedef unsigned long long ull_t;

__device__ __forceinline__ unsigned short f2bf(float f) {
  unsigned u = __builtin_bit_cast(unsigned, f);
  u += 0x7fffu + ((u >> 16) & 1u);
  return (unsigned short)(u >> 16);
}

__device__ __forceinline__ float fexp2(float x) {
  return __builtin_amdgcn_exp2f(x);
}

__device__ __forceinline__ float bf2f(unsigned short v) {
  unsigned u = (unsigned)v << 16;
  return __builtin_bit_cast(float, u);
}

__device__ __forceinline__ short8 load8f(const float* p) {
  float4 v0 = *(const float4*)p;
  float4 v1 = *(const float4*)(p + 4);
  short8 r;
  r[0] = (short)f2bf(v0.x); r[1] = (short)f2bf(v0.y);
  r[2] = (short)f2bf(v0.z); r[3] = (short)f2bf(v0.w);
  r[4] = (short)f2bf(v1.x); r[5] = (short)f2bf(v1.y);
  r[6] = (short)f2bf(v1.z); r[7] = (short)f2bf(v1.w);
  return r;
}

__device__ __forceinline__ f32x4 mfma16(short8 a, short8 b, f32x4 c) {
  return __builtin_amdgcn_mfma_f32_16x16x32_bf16(a, b, c, 0, 0, 0);
}

// ---- prep: W f32->bf16 + X (q,k,v inputs) f32->bf16 + mask -> bitwords
__global__ __launch_bounds__(256) void prep_kernel(
    const void* __restrict__ maskp,
    const float* __restrict__ Wq, const float* __restrict__ Wk,
    const float* __restrict__ Wv, const float* __restrict__ Wo,
    const float* __restrict__ Xq, const float* __restrict__ Xk,
    const float* __restrict__ Xv,
    ull_t* __restrict__ mout, ushort_t* __restrict__ Wb,
    ushort_t* __restrict__ Xb)
{
  const int bid = blockIdx.x;
  if (bid < 16) {
    const int g = bid * 256 + threadIdx.x;       // 4096 threads
    #pragma unroll
    for (int it = 0; it < 8; ++it) {
      const int grp = g + it * 4096;             // 32768 short8-groups total
      const int w = grp >> 13;                   // 8192 groups per matrix
      const int off = (grp & 8191) * 8;
      const float* src = w == 0 ? Wq : w == 1 ? Wk : w == 2 ? Wv : Wo;
      *(short8*)(Wb + w * 65536 + off) = load8f(src + off);
    }
    return;
  }
  if (bid < 784) {
    const int g0 = (bid - 16) * 2048 + threadIdx.x;
    #pragma unroll
    for (int it = 0; it < 8; ++it) {
      const int grp = g0 + it * 256;             // 1572864 groups total
      const int w = grp >> 19;                   // 524288 groups per matrix
      const int off = (grp & 524287) * 8;
      const float* src = w == 0 ? Xq : w == 1 ? Xk : Xv;
      *(short8*)(Xb + (size_t)w * 4194304 + off) = load8f(src + off);
    }
    return;
  }
  const int l = threadIdx.x & 63;
  const unsigned probe = ((const unsigned*)maskp)[l];
  const int isbyte = __any(probe > 1u);
  const int gwave = ((bid - 784) * 256 + threadIdx.x) >> 6;
  const int nwaves = (gridDim.x - 784) * 4;
  const long long total4 = (long long)Bn * SQn * (SKn / 256);  // 4-word groups
  if (isbyte) {
    for (long long w = gwave; w < total4; w += nwaves) {
      const unsigned char* mp = (const unsigned char*)maskp + w * 256;
      bool n0 = mp[l] != 0,        n1 = mp[64 + l] != 0;
      bool n2 = mp[128 + l] != 0,  n3 = mp[192 + l] != 0;
      ull_t b0 = __ballot(n0), b1 = __ballot(n1);
      ull_t b2 = __ballot(n2), b3 = __ballot(n3);
      if (l == 0) {
        mout[w * 4] = b0; mout[w * 4 + 1] = b1;
        mout[w * 4 + 2] = b2; mout[w * 4 + 3] = b3;
      }
    }
  } else {
    for (long long w = gwave; w < total4; w += nwaves) {
      const int* mp = (const int*)maskp + w * 256;
      bool n0 = mp[l] != 0,        n1 = mp[64 + l] != 0;
      bool n2 = mp[128 + l] != 0,  n3 = mp[192 + l] != 0;
      ull_t b0 = __ballot(n0), b1 = __ballot(n1);
      ull_t b2 = __ballot(n2), b3 = __ballot(n3);
      if (l == 0) {
        mout[w * 4] = b0; mout[w * 4 + 1] = b1;
        mout[w * 4 + 2] = b2; mout[w * 4 + 3] = b3;
      }
    }
  }
}

// ------------------------------------- fused Q/K/V projection GEMMs
__global__ __launch_bounds__(256) void proj3_kernel(
    const ushort_t* __restrict__ Xb, const ushort_t* __restrict__ Wb,
    const float* __restrict__ bqp, const float* __restrict__ bkp,
    const float* __restrict__ bvp,
    ushort_t* __restrict__ Qb, ushort_t* __restrict__ Kb,
    ushort_t* __restrict__ Vt)
{
  const int which = blockIdx.z;
  const ushort_t* X = Xb + (size_t)which * 4194304;
  const ushort_t* W = Wb + which * 65536;
  const float* bias = which == 0 ? bqp : which == 1 ? bkp : bvp;
  ushort_t* Y = which == 0 ? Qb : which == 1 ? Kb : Vt;
  const int vtrans = (which == 2);

  const int m0 = blockIdx.x * 64;
  const int n0 = blockIdx.y * 64;
  const int wv = threadIdx.x >> 6;
  const int l  = threadIdx.x & 63;
  const int lr = l & 15, lg = l >> 4;
  const int mrow = m0 + wv * 16 + lr;

  f32x4 acc[4];
  #pragma unroll
  for (int t = 0; t < 4; ++t) acc[t] = (f32x4){0.f, 0.f, 0.f, 0.f};

  const ushort_t* ap = X + (size_t)mrow * Hn + lg * 8;
  for (int k0 = 0; k0 < Hn; k0 += 32) {
    short8 a = *(const short8*)(ap + k0);
    #pragma unroll
    for (int t = 0; t < 4; ++t) {
      short8 bb = *(const short8*)(W + (size_t)(n0 + t * 16 + lr) * Hn + k0 + lg * 8);
      acc[t] = mfma16(a, bb, acc[t]);
    }
  }

  #pragma unroll
  for (int t = 0; t < 4; ++t) {
    const int n = n0 + t * 16 + lr;
    const float bv = bias[n];
    const int h = n >> 6, d = n & 63;
    if (!vtrans) {
      #pragma unroll
      for (int r = 0; r < 4; ++r) {
        const int m = m0 + wv * 16 + lg * 4 + r;
        const int bb = m >> 11, s = m & 2047;
        size_t idx = (((size_t)bb * NHn + h) * SQn + s) * HDn + d;
        Y[idx] = f2bf(acc[t][r] + bv);
      }
    } else {
      const int m = m0 + wv * 16 + lg * 4;
      const int bb = m >> 11, s = m & 2047;
      ushort4 pk;
      pk.x = f2bf(acc[t][0] + bv); pk.y = f2bf(acc[t][1] + bv);
      pk.z = f2bf(acc[t][2] + bv); pk.w = f2bf(acc[t][3] + bv);
      size_t idx = (((size_t)bb * NHn + h) * HDn + d) * (size_t)SKn + s;
      *(ushort4*)(Y + idx) = pk;
    }
  }
}

// ------------------------------------------- single-pass fused attention
// R19: 1024-thread blocks = 2 row-groups x 8 col-waves. Each WAVE is
// byte-identical to the proven R9 wave (16 rows x 256 cols, ~110-reg live
// set, no spill at the 128 budget), but one BLOCK now covers 32 q-rows per
// K/V read pass -> the kernel's K/V L2-read volume halves (2.1 -> 1.05 GB).
// Column coverage audited (R12 lesson): 8 col-waves x 256 = 2048. Epilogue
// reuses one Opart buffer in two passes (row-group 0, then 1): LDS 34.8 KB.
// Same residency as R9: 16 waves/CU (1 block/CU, waves_per_eu(4,4)).
__global__ __launch_bounds__(1024)
__attribute__((amdgpu_waves_per_eu(4, 4)))
void fused_attn_kernel(
    const ushort_t* __restrict__ Qb, const ushort_t* __restrict__ Kb,
    const ushort_t* __restrict__ Vt, const unsigned* __restrict__ maskbits,
    float* __restrict__ attn_out, ushort_t* __restrict__ Ob)
{
  __shared__ float red[16][16];       // 1 KiB
  __shared__ float Opart[8][16][66];  // 33 KiB, +2 pad kills bank conflicts

  const int bid = blockIdx.x;
  const int rt = (bid & 7) * 256 + (bid >> 3);  // 2048 blocks, XCD bijection
  const int wv = threadIdx.x >> 6;        // 0..15
  const int g  = wv >> 3;                 // row-group 0/1
  const int cw = wv & 7;                  // col-wave 0..7
  const int l  = threadIdx.x & 63;
  const int lr = l & 15, lg = l >> 4;
  const int bh = rt >> 6;                 // 64 row-tiles (32 rows) per (b,h)
  const int q0 = (rt & 63) << 5;
  const int b  = bh >> 2, h = bh & 3;
  const int colbase = cw * 256;
  const int qrow = q0 + g * 16;           // this wave's 16-row base

  const ushort_t* Qh = Qb + (size_t)bh * SQn * HDn;
  const ushort_t* Kh = Kb + (size_t)bh * SKn * HDn;
  const ushort_t* Vh = Vt + (size_t)bh * HDn * SKn;

  short8 qa0 = *(const short8*)(Qh + (qrow + lr) * HDn + lg * 8);
  short8 qa1 = *(const short8*)(Qh + (qrow + lr) * HDn + 32 + lg * 8);

  const int krA = (lr >> 2) * 8 + (lr & 3);
  const unsigned* mrow = maskbits + ((size_t)b * SQn + qrow + lr) * (SKn / 32) + cw * 8;
  const int bsh = lg * 8;

  // ---- Phase A: QK^T once; packed p-hat + row-sum + unnormalized PV
  short8 pf8[8];
  float lsum = 0.f;
  f32x4 oacc[4];
  #pragma unroll
  for (int dt = 0; dt < 4; ++dt) oacc[dt] = (f32x4){0.f, 0.f, 0.f, 0.f};

  u32x4 mw = *(const u32x4*)mrow;   // second half loaded at s8==4
  #pragma unroll
  for (int s8 = 0; s8 < 8; ++s8) {
    if (s8 == 4) mw = *(const u32x4*)(mrow + 4);
    const int c = colbase + s8 * 32;
    const ushort_t* kp = Kh + (size_t)(c + krA) * HDn + lg * 8;
    short8 ka0 = *(const short8*)(kp);
    short8 ka1 = *(const short8*)(kp + 32);
    short8 kb0 = *(const short8*)(kp + 4 * HDn);
    short8 kb1 = *(const short8*)(kp + 4 * HDn + 32);
    f32x4 za = (f32x4){0.f, 0.f, 0.f, 0.f}, zb = (f32x4){0.f, 0.f, 0.f, 0.f};
    za = mfma16(ka0, qa0, za); za = mfma16(ka1, qa1, za);
    zb = mfma16(kb0, qa0, zb); zb = mfma16(kb1, qa1, zb);

    // V loads issued here: K regs dead, exp/pack VALU below hides latency
    const ushort_t* vp = Vh + (size_t)lr * SKn + c + lg * 8;
    short8 vb0 = *(const short8*)(vp);
    short8 vb1 = *(const short8*)(vp + 16 * SKn);
    short8 vb2 = *(const short8*)(vp + 32 * SKn);
    short8 vb3 = *(const short8*)(vp + 48 * SKn);

    const unsigned bits = (mw[s8 & 3] >> bsh) & 0xFFu;
    short8 pf;
    #pragma unroll
    for (int j = 0; j < 4; ++j) {
      float pa = ((bits >> j) & 1) ? fexp2(za[j] * SCALE2) : 0.f;
      float pb = ((bits >> (4 + j)) & 1) ? fexp2(zb[j] * SCALE2) : 0.f;
      lsum += pa + pb;
      pf[j] = (short)f2bf(pa);
      pf[4 + j] = (short)f2bf(pb);
    }
    pf8[s8] = pf;
    oacc[0] = mfma16(pf, vb0, oacc[0]);
    oacc[1] = mfma16(pf, vb1, oacc[1]);
    oacc[2] = mfma16(pf, vb2, oacc[2]);
    oacc[3] = mfma16(pf, vb3, oacc[3]);
  }

  // row-sum across the 4 lane-groups sharing row lr
  lsum += __shfl_xor(lsum, 16);
  lsum += __shfl_xor(lsum, 32);
  if (l < 16) red[wv][lr] = lsum;
  // row-group 0 stashes its O partials before the first barrier
  if (g == 0) {
    #pragma unroll
    for (int dt = 0; dt < 4; ++dt)
      #pragma unroll
      for (int r = 0; r < 4; ++r)
        Opart[cw][lg * 4 + r][dt * 16 + lr] = oacc[dt][r];
  }
  __syncthreads();

  // per-row softmax denominator for THIS wave's row group
  float gsum = 0.f;
  #pragma unroll
  for (int ww = 0; ww < 8; ++ww) gsum += red[g * 8 + ww][lr];
  const bool rowempty = (gsum == 0.f);   // fully-masked row (exact)
  const float rinv = rowempty ? 0.f : 1.f / gsum;

  // ---- Phase B: attn = bf16(p-hat) * rinv, plain cached stores
  float* arow = attn_out + ((size_t)bh * SQn + qrow + lr) * (size_t)SKn;
  #pragma unroll
  for (int s8 = 0; s8 < 8; ++s8) {
    const int c = colbase + s8 * 32;
    float av[8];
    #pragma unroll
    for (int j = 0; j < 8; ++j)
      av[j] = bf2f((unsigned short)pf8[s8][j]) * rinv;
    if (rowempty && s8 == 0 && cw == 0 && lg == 0) av[0] = 1.f;  // one-hot key 0
    *(f32x4*)(arow + c + lg * 8)     = (f32x4){av[0], av[1], av[2], av[3]};
    *(f32x4*)(arow + c + lg * 8 + 4) = (f32x4){av[4], av[5], av[6], av[7]};
  }

  // ---- epilogue pass 1: reduce+store row-group 0 (rows q0 .. q0+15)
  {
    const int row = threadIdx.x >> 6, d = threadIdx.x & 63;  // 1024 = 16x64
    float gs = 0.f;
    #pragma unroll
    for (int ww = 0; ww < 8; ++ww) gs += red[ww][row];
    float s = 0.f;
    #pragma unroll
    for (int ww = 0; ww < 8; ++ww) s += Opart[ww][row][d];
    float val = (gs == 0.f) ? bf2f(Vh[(size_t)d * SKn]) : s / gs;
    Ob[((size_t)b * SQn + q0 + row) * Hn + h * HDn + d] = f2bf(val);
  }
  __syncthreads();

  // ---- epilogue pass 2: row-group 1 reuses the same Opart buffer
  if (g == 1) {
    #pragma unroll
    for (int dt = 0; dt < 4; ++dt)
      #pragma unroll
      for (int r = 0; r < 4; ++r)
        Opart[cw][lg * 4 + r][dt * 16 + lr] = oacc[dt][r];
  }
  __syncthreads();

  {
    const int row = threadIdx.x >> 6, d = threadIdx.x & 63;
    float gs = 0.f;
    #pragma unroll
    for (int ww = 0; ww < 8; ++ww) gs += red[8 + ww][row];
    float s = 0.f;
    #pragma unroll
    for (int ww = 0; ww < 8; ++ww) s += Opart[ww][row][d];
    float val = (gs == 0.f) ? bf2f(Vh[(size_t)d * SKn]) : s / gs;
    Ob[((size_t)b * SQn + q0 + 16 + row) * Hn + h * HDn + d] = f2bf(val);
  }
}

// ------------------------------------------------ output projection (bf16 A,W)
__global__ __launch_bounds__(256) void oproj_kernel(
    const unsigned short* __restrict__ A, const ushort_t* __restrict__ Wob,
    const float* __restrict__ bias, float* __restrict__ out)
{
  const int m0 = blockIdx.x * 64;
  const int n0 = blockIdx.y * 64;
  const int wv = threadIdx.x >> 6;
  const int l  = threadIdx.x & 63;
  const int lr = l & 15, lg = l >> 4;
  const int mrow = m0 + wv * 16 + lr;

  f32x4 acc[4];
  #pragma unroll
  for (int t = 0; t < 4; ++t) acc[t] = (f32x4){0.f, 0.f, 0.f, 0.f};

  for (int k0 = 0; k0 < Hn; k0 += 32) {
    short8 a = *(const short8*)(A + (size_t)mrow * Hn + k0 + lg * 8);
    #pragma unroll
    for (int t = 0; t < 4; ++t) {
      short8 bb = *(const short8*)(Wob + (size_t)(n0 + t * 16 + lr) * Hn + k0 + lg * 8);
      acc[t] = mfma16(a, bb, acc[t]);
    }
  }
  #pragma unroll
  for (int t = 0; t < 4; ++t) {
    const int n = n0 + t * 16 + lr;
    const float bv = bias[n];
    #pragma unroll
    for (int r = 0; r < 4; ++r) {
      const int m = m0 + wv * 16 + lg * 4 + r;
      out[(size_t)m * Hn + n] = acc[t][r] + bv;
    }
  }
}

extern "C" void kernel_launch(void* const* d_in, const int* in_sizes, int n_in,
                              void* d_out, int out_size, void* d_ws, size_t ws_size,
                              hipStream_t stream) {
  const float* query = (const float*)d_in[0];
  const float* key_  = (const float*)d_in[1];
  const float* value = (const float*)d_in[2];
  const void*  mask  = d_in[3];
  const float* Wq = (const float*)d_in[4];
  const float* bq = (const float*)d_in[5];
  const float* Wk = (const float*)d_in[6];
  const float* bk = (const float*)d_in[7];
  const float* Wv = (const float*)d_in[8];
  const float* bv = (const float*)d_in[9];
  const float* Wo = (const float*)d_in[10];
  const float* bo = (const float*)d_in[11];

  float* out  = (float*)d_out;
  float* attn = out + (size_t)Bn * SQn * Hn;

  char* ws = (char*)d_ws;
  unsigned short* Qb = (unsigned short*)ws;
  unsigned short* Kb = Qb + (size_t)Bn * SQn * Hn;
  unsigned short* Vt = Kb + (size_t)Bn * SKn * Hn;
  unsigned short* Ob = Vt + (size_t)Bn * SKn * Hn;
  unsigned* mbits = (unsigned*)(Ob + (size_t)Bn * SQn * Hn);     // 4 MiB
  ushort_t* Wb = (ushort_t*)(mbits + (size_t)Bn * SQn * (SKn / 32));  // 512 KiB
  // X bf16 scratch in the attn output region: written by prep, read by
  // proj3, then overwritten by fused_attn_kernel (stream-ordered, safe).
  ushort_t* Xb = (ushort_t*)attn;

  prep_kernel<<<1808, 256, 0, stream>>>(mask, Wq, Wk, Wv, Wo,
                                        query, key_, value,
                                        (ull_t*)mbits, Wb, Xb);
  proj3_kernel<<<dim3(256, 4, 3), 256, 0, stream>>>(
      Xb, Wb, bq, bk, bv, Qb, Kb, Vt);
  fused_attn_kernel<<<2048, 1024, 0, stream>>>(Qb, Kb, Vt, mbits, attn, Ob);
  oproj_kernel<<<dim3(256, 4), 256, 0, stream>>>(Ob, Wb + 3 * 65536, bo, out);
}

// Round 20
// 452.362 us; speedup vs baseline: 1.0746x; 1.0658x over previous
//
#include <hip/hip_runtime.h>
#include <math.h>

#define Bn  8
#define SQn 2048
#define SKn 2048
#define Hn  256
#define NHn 4
#define HDn 64
#define SCALE2 0.1803368801111f   /* 0.125 * log2(e) */

typedef __attribute__((ext_vector_type(4))) float f32x4;
typedef __attribute__((ext_vector_type(4))) unsigned int u32x4;
typedef __attribute__((ext_vector_type(8))) short short8;
typedef unsigned short ushort_t;
typedef unsigned long long ull_t;

__device__ __forceinline__ unsigned short f2bf(float f) {
  unsigned u = __builtin_bit_cast(unsigned, f);
  u += 0x7fffu + ((u >> 16) & 1u);
  return (unsigned short)(u >> 16);
}

__device__ __forceinline__ float fexp2(float x) {
  return __builtin_amdgcn_exp2f(x);
}

__device__ __forceinline__ float bf2f(unsigned short v) {
  unsigned u = (unsigned)v << 16;
  return __builtin_bit_cast(float, u);
}

__device__ __forceinline__ short8 load8f(const float* p) {
  float4 v0 = *(const float4*)p;
  float4 v1 = *(const float4*)(p + 4);
  short8 r;
  r[0] = (short)f2bf(v0.x); r[1] = (short)f2bf(v0.y);
  r[2] = (short)f2bf(v0.z); r[3] = (short)f2bf(v0.w);
  r[4] = (short)f2bf(v1.x); r[5] = (short)f2bf(v1.y);
  r[6] = (short)f2bf(v1.z); r[7] = (short)f2bf(v1.w);
  return r;
}

__device__ __forceinline__ f32x4 mfma16(short8 a, short8 b, f32x4 c) {
  return __builtin_amdgcn_mfma_f32_16x16x32_bf16(a, b, c, 0, 0, 0);
}

// ---- prep: W f32->bf16 + X (q,k,v inputs) f32->bf16 + mask -> bitwords
__global__ __launch_bounds__(256) void prep_kernel(
    const void* __restrict__ maskp,
    const float* __restrict__ Wq, const float* __restrict__ Wk,
    const float* __restrict__ Wv, const float* __restrict__ Wo,
    const float* __restrict__ Xq, const float* __restrict__ Xk,
    const float* __restrict__ Xv,
    ull_t* __restrict__ mout, ushort_t* __restrict__ Wb,
    ushort_t* __restrict__ Xb)
{
  const int bid = blockIdx.x;
  if (bid < 16) {
    const int g = bid * 256 + threadIdx.x;       // 4096 threads
    #pragma unroll
    for (int it = 0; it < 8; ++it) {
      const int grp = g + it * 4096;             // 32768 short8-groups total
      const int w = grp >> 13;                   // 8192 groups per matrix
      const int off = (grp & 8191) * 8;
      const float* src = w == 0 ? Wq : w == 1 ? Wk : w == 2 ? Wv : Wo;
      *(short8*)(Wb + w * 65536 + off) = load8f(src + off);
    }
    return;
  }
  if (bid < 784) {
    const int g0 = (bid - 16) * 2048 + threadIdx.x;
    #pragma unroll
    for (int it = 0; it < 8; ++it) {
      const int grp = g0 + it * 256;             // 1572864 groups total
      const int w = grp >> 19;                   // 524288 groups per matrix
      const int off = (grp & 524287) * 8;
      const float* src = w == 0 ? Xq : w == 1 ? Xk : Xv;
      *(short8*)(Xb + (size_t)w * 4194304 + off) = load8f(src + off);
    }
    return;
  }
  const int l = threadIdx.x & 63;
  const unsigned probe = ((const unsigned*)maskp)[l];
  const int isbyte = __any(probe > 1u);
  const int gwave = ((bid - 784) * 256 + threadIdx.x) >> 6;
  const int nwaves = (gridDim.x - 784) * 4;
  const long long total4 = (long long)Bn * SQn * (SKn / 256);  // 4-word groups
  if (isbyte) {
    for (long long w = gwave; w < total4; w += nwaves) {
      const unsigned char* mp = (const unsigned char*)maskp + w * 256;
      bool n0 = mp[l] != 0,        n1 = mp[64 + l] != 0;
      bool n2 = mp[128 + l] != 0,  n3 = mp[192 + l] != 0;
      ull_t b0 = __ballot(n0), b1 = __ballot(n1);
      ull_t b2 = __ballot(n2), b3 = __ballot(n3);
      if (l == 0) {
        mout[w * 4] = b0; mout[w * 4 + 1] = b1;
        mout[w * 4 + 2] = b2; mout[w * 4 + 3] = b3;
      }
    }
  } else {
    for (long long w = gwave; w < total4; w += nwaves) {
      const int* mp = (const int*)maskp + w * 256;
      bool n0 = mp[l] != 0,        n1 = mp[64 + l] != 0;
      bool n2 = mp[128 + l] != 0,  n3 = mp[192 + l] != 0;
      ull_t b0 = __ballot(n0), b1 = __ballot(n1);
      ull_t b2 = __ballot(n2), b3 = __ballot(n3);
      if (l == 0) {
        mout[w * 4] = b0; mout[w * 4 + 1] = b1;
        mout[w * 4 + 2] = b2; mout[w * 4 + 3] = b3;
      }
    }
  }
}

// ------------------------------------- fused Q/K/V projection GEMMs
__global__ __launch_bounds__(256) void proj3_kernel(
    const ushort_t* __restrict__ Xb, const ushort_t* __restrict__ Wb,
    const float* __restrict__ bqp, const float* __restrict__ bkp,
    const float* __restrict__ bvp,
    ushort_t* __restrict__ Qb, ushort_t* __restrict__ Kb,
    ushort_t* __restrict__ Vt)
{
  const int which = blockIdx.z;
  const ushort_t* X = Xb + (size_t)which * 4194304;
  const ushort_t* W = Wb + which * 65536;
  const float* bias = which == 0 ? bqp : which == 1 ? bkp : bvp;
  ushort_t* Y = which == 0 ? Qb : which == 1 ? Kb : Vt;
  const int vtrans = (which == 2);

  const int m0 = blockIdx.x * 64;
  const int n0 = blockIdx.y * 64;
  const int wv = threadIdx.x >> 6;
  const int l  = threadIdx.x & 63;
  const int lr = l & 15, lg = l >> 4;
  const int mrow = m0 + wv * 16 + lr;

  f32x4 acc[4];
  #pragma unroll
  for (int t = 0; t < 4; ++t) acc[t] = (f32x4){0.f, 0.f, 0.f, 0.f};

  const ushort_t* ap = X + (size_t)mrow * Hn + lg * 8;
  for (int k0 = 0; k0 < Hn; k0 += 32) {
    short8 a = *(const short8*)(ap + k0);
    #pragma unroll
    for (int t = 0; t < 4; ++t) {
      short8 bb = *(const short8*)(W + (size_t)(n0 + t * 16 + lr) * Hn + k0 + lg * 8);
      acc[t] = mfma16(a, bb, acc[t]);
    }
  }

  #pragma unroll
  for (int t = 0; t < 4; ++t) {
    const int n = n0 + t * 16 + lr;
    const float bv = bias[n];
    const int h = n >> 6, d = n & 63;
    if (!vtrans) {
      #pragma unroll
      for (int r = 0; r < 4; ++r) {
        const int m = m0 + wv * 16 + lg * 4 + r;
        const int bb = m >> 11, s = m & 2047;
        size_t idx = (((size_t)bb * NHn + h) * SQn + s) * HDn + d;
        Y[idx] = f2bf(acc[t][r] + bv);
      }
    } else {
      const int m = m0 + wv * 16 + lg * 4;
      const int bb = m >> 11, s = m & 2047;
      ushort4 pk;
      pk.x = f2bf(acc[t][0] + bv); pk.y = f2bf(acc[t][1] + bv);
      pk.z = f2bf(acc[t][2] + bv); pk.w = f2bf(acc[t][3] + bv);
      size_t idx = (((size_t)bb * NHn + h) * HDn + d) * (size_t)SKn + s;
      *(ushort4*)(Y + idx) = pk;
    }
  }
}

// ------------------------------------------- single-pass fused attention
// R20 = R9 structure with IDENTITY K-row placement (tile A rows c+lr, tile
// B rows c+16+lr) so lane (lr,lg) holds cols {c+4lg..+3} U {c+16+4lg..+3}.
// Phase-B stores are then 16B at stride-16B across the 4 lg lanes: each
// store instruction covers 16 rows x FULLY-USED 64B lines -> store
// transactions halve vs R9's half-used 32B-stride pattern (the last
// unexplained 2x in the per-wave transaction budget; R19 falsified the
// volume theory, tx theory survived). PV's A-fragment (8-contiguous k) is
// rebuilt by an 8-shfl+4-select butterfly per chunk (+~96 VALU/wave).
__global__ __launch_bounds__(512)
__attribute__((amdgpu_waves_per_eu(4, 4)))
void fused_attn_kernel(
    const ushort_t* __restrict__ Qb, const ushort_t* __restrict__ Kb,
    const ushort_t* __restrict__ Vt, const unsigned* __restrict__ maskbits,
    float* __restrict__ attn_out, ushort_t* __restrict__ Ob)
{
  __shared__ float red[8][16];
  __shared__ float Opart[8][16][66];  // +2 pad kills bank conflicts

  const int bid = blockIdx.x;
  const int rt = (bid & 7) * 512 + (bid >> 3);  // XCD-chunked bijection
  const int wv = threadIdx.x >> 6;
  const int l  = threadIdx.x & 63;
  const int lr = l & 15, lg = l >> 4;
  const int bh = rt >> 7;
  const int q0 = (rt & 127) << 4;
  const int b  = bh >> 2, h = bh & 3;
  const int colbase = wv * 256;

  const ushort_t* Qh = Qb + (size_t)bh * SQn * HDn;
  const ushort_t* Kh = Kb + (size_t)bh * SKn * HDn;
  const ushort_t* Vh = Vt + (size_t)bh * HDn * SKn;

  short8 qa0 = *(const short8*)(Qh + (q0 + lr) * HDn + lg * 8);
  short8 qa1 = *(const short8*)(Qh + (q0 + lr) * HDn + 32 + lg * 8);

  const unsigned* mrow = maskbits + ((size_t)b * SQn + q0 + lr) * (SKn / 32) + wv * 8;
  // shuffle sources for the PV-order rebuild
  const int srcLo = lr + (((2 * lg) & 3) << 4);
  const int srcHi = lr + (((2 * lg + 1) & 3) << 4);
  const bool useB = (lg >= 2);

  // ---- Phase A: QK^T once; packed p-hat + row-sum + unnormalized PV
  u32x4 pk8[8];     // own-order p-hat bf16 (cols 4lg..+3, 16+4lg..+3)
  float lsum = 0.f;
  f32x4 oacc[4];
  #pragma unroll
  for (int dt = 0; dt < 4; ++dt) oacc[dt] = (f32x4){0.f, 0.f, 0.f, 0.f};

  u32x4 mw = *(const u32x4*)mrow;   // second half loaded at s8==4
  #pragma unroll
  for (int s8 = 0; s8 < 8; ++s8) {
    if (s8 == 4) mw = *(const u32x4*)(mrow + 4);
    const int c = colbase + s8 * 32;
    // identity placement: tile A = K rows c..c+15, tile B = c+16..c+31
    const ushort_t* kp = Kh + (size_t)(c + lr) * HDn + lg * 8;
    short8 ka0 = *(const short8*)(kp);
    short8 ka1 = *(const short8*)(kp + 32);
    short8 kb0 = *(const short8*)(kp + 16 * HDn);
    short8 kb1 = *(const short8*)(kp + 16 * HDn + 32);
    f32x4 za = (f32x4){0.f, 0.f, 0.f, 0.f}, zb = (f32x4){0.f, 0.f, 0.f, 0.f};
    za = mfma16(ka0, qa0, za); za = mfma16(ka1, qa1, za);
    zb = mfma16(kb0, qa0, zb); zb = mfma16(kb1, qa1, zb);
    // za[j] = score col c+4lg+j ; zb[j] = col c+16+4lg+j

    // V loads (PV B-operand, unchanged 16B/lane)
    const ushort_t* vp = Vh + (size_t)lr * SKn + c + lg * 8;
    short8 vb0 = *(const short8*)(vp);
    short8 vb1 = *(const short8*)(vp + 16 * SKn);
    short8 vb2 = *(const short8*)(vp + 32 * SKn);
    short8 vb3 = *(const short8*)(vp + 48 * SKn);

    const unsigned word = mw[s8 & 3];
    const unsigned bitsA = (word >> (lg * 4)) & 0xFu;
    const unsigned bitsB = (word >> (16 + lg * 4)) & 0xFu;
    float pa[4], pb[4];
    #pragma unroll
    for (int j = 0; j < 4; ++j) {
      pa[j] = ((bitsA >> j) & 1) ? fexp2(za[j] * SCALE2) : 0.f;
      pb[j] = ((bitsB >> j) & 1) ? fexp2(zb[j] * SCALE2) : 0.f;
      lsum += pa[j] + pb[j];
    }
    unsigned a01 = (unsigned)f2bf(pa[0]) | ((unsigned)f2bf(pa[1]) << 16);
    unsigned a23 = (unsigned)f2bf(pa[2]) | ((unsigned)f2bf(pa[3]) << 16);
    unsigned b01 = (unsigned)f2bf(pb[0]) | ((unsigned)f2bf(pb[1]) << 16);
    unsigned b23 = (unsigned)f2bf(pb[2]) | ((unsigned)f2bf(pb[3]) << 16);
    pk8[s8] = (u32x4){a01, a23, b01, b23};

    // rebuild PV A-frag (k = 8lg..8lg+7 contiguous) via butterfly:
    // dw0/1 from lane (2lg)&3, dw2/3 from (2lg+1)&3; A-half lg<2, B-half lg>=2
    unsigned sAl0 = __shfl((int)a01, srcLo), sAl1 = __shfl((int)a23, srcLo);
    unsigned sAh0 = __shfl((int)a01, srcHi), sAh1 = __shfl((int)a23, srcHi);
    unsigned sBl0 = __shfl((int)b01, srcLo), sBl1 = __shfl((int)b23, srcLo);
    unsigned sBh0 = __shfl((int)b01, srcHi), sBh1 = __shfl((int)b23, srcHi);
    u32x4 pfd;
    pfd[0] = useB ? sBl0 : sAl0;
    pfd[1] = useB ? sBl1 : sAl1;
    pfd[2] = useB ? sBh0 : sAh0;
    pfd[3] = useB ? sBh1 : sAh1;
    short8 pf = __builtin_bit_cast(short8, pfd);
    oacc[0] = mfma16(pf, vb0, oacc[0]);
    oacc[1] = mfma16(pf, vb1, oacc[1]);
    oacc[2] = mfma16(pf, vb2, oacc[2]);
    oacc[3] = mfma16(pf, vb3, oacc[3]);
  }

  // row-sum across the 4 lane-groups sharing row lr; stash partial O
  lsum += __shfl_xor(lsum, 16);
  lsum += __shfl_xor(lsum, 32);
  if (l < 16) red[wv][lr] = lsum;
  #pragma unroll
  for (int dt = 0; dt < 4; ++dt)
    #pragma unroll
    for (int r = 0; r < 4; ++r)
      Opart[wv][lg * 4 + r][dt * 16 + lr] = oacc[dt][r];
  __syncthreads();

  float gsum = 0.f;
  #pragma unroll
  for (int ww = 0; ww < 8; ++ww) gsum += red[ww][lr];
  const bool rowempty = (gsum == 0.f);   // fully-masked row (exact)
  const float rinv = rowempty ? 0.f : 1.f / gsum;

  // ---- Phase B: attn = bf16(p-hat) * rinv; 16B stores at 16B lane stride
  // -> each instruction covers 16 rows x fully-used 64B (halved tx)
  float* arow = attn_out + ((size_t)bh * SQn + q0 + lr) * (size_t)SKn;
  #pragma unroll
  for (int s8 = 0; s8 < 8; ++s8) {
    const int c = colbase + s8 * 32;
    u32x4 pk = pk8[s8];
    float avA[4], avB[4];
    #pragma unroll
    for (int j = 0; j < 2; ++j) {
      avA[2 * j]     = bf2f((unsigned short)(pk[j] & 0xFFFFu)) * rinv;
      avA[2 * j + 1] = bf2f((unsigned short)(pk[j] >> 16)) * rinv;
      avB[2 * j]     = bf2f((unsigned short)(pk[2 + j] & 0xFFFFu)) * rinv;
      avB[2 * j + 1] = bf2f((unsigned short)(pk[2 + j] >> 16)) * rinv;
    }
    if (rowempty && s8 == 0 && wv == 0 && lg == 0) avA[0] = 1.f;  // one-hot key 0
    *(f32x4*)(arow + c + lg * 4)      = (f32x4){avA[0], avA[1], avA[2], avA[3]};
    *(f32x4*)(arow + c + 16 + lg * 4) = (f32x4){avB[0], avB[1], avB[2], avB[3]};
  }

  // ---- epilogue: cross-wave O reduce, scale by 1/gsum per row
  #pragma unroll
  for (int e = threadIdx.x; e < 1024; e += 512) {
    const int row = e >> 6, d = e & 63;
    float gs = 0.f;
    #pragma unroll
    for (int ww = 0; ww < 8; ++ww) gs += red[ww][row];
    float s = 0.f;
    #pragma unroll
    for (int ww = 0; ww < 8; ++ww) s += Opart[ww][row][d];
    float val;
    if (gs == 0.f) {  // fully-masked row: attn=one-hot(key0) -> O=V[:,0]
      val = bf2f(Vh[(size_t)d * SKn]);
    } else {
      val = s / gs;
    }
    Ob[((size_t)b * SQn + q0 + row) * Hn + h * HDn + d] = f2bf(val);
  }
}

// ------------------------------------------------ output projection (bf16 A,W)
__global__ __launch_bounds__(256) void oproj_kernel(
    const unsigned short* __restrict__ A, const ushort_t* __restrict__ Wob,
    const float* __restrict__ bias, float* __restrict__ out)
{
  const int m0 = blockIdx.x * 64;
  const int n0 = blockIdx.y * 64;
  const int wv = threadIdx.x >> 6;
  const int l  = threadIdx.x & 63;
  const int lr = l & 15, lg = l >> 4;
  const int mrow = m0 + wv * 16 + lr;

  f32x4 acc[4];
  #pragma unroll
  for (int t = 0; t < 4; ++t) acc[t] = (f32x4){0.f, 0.f, 0.f, 0.f};

  for (int k0 = 0; k0 < Hn; k0 += 32) {
    short8 a = *(const short8*)(A + (size_t)mrow * Hn + k0 + lg * 8);
    #pragma unroll
    for (int t = 0; t < 4; ++t) {
      short8 bb = *(const short8*)(Wob + (size_t)(n0 + t * 16 + lr) * Hn + k0 + lg * 8);
      acc[t] = mfma16(a, bb, acc[t]);
    }
  }
  #pragma unroll
  for (int t = 0; t < 4; ++t) {
    const int n = n0 + t * 16 + lr;
    const float bv = bias[n];
    #pragma unroll
    for (int r = 0; r < 4; ++r) {
      const int m = m0 + wv * 16 + lg * 4 + r;
      out[(size_t)m * Hn + n] = acc[t][r] + bv;
    }
  }
}

extern "C" void kernel_launch(void* const* d_in, const int* in_sizes, int n_in,
                              void* d_out, int out_size, void* d_ws, size_t ws_size,
                              hipStream_t stream) {
  const float* query = (const float*)d_in[0];
  const float* key_  = (const float*)d_in[1];
  const float* value = (const float*)d_in[2];
  const void*  mask  = d_in[3];
  const float* Wq = (const float*)d_in[4];
  const float* bq = (const float*)d_in[5];
  const float* Wk = (const float*)d_in[6];
  const float* bk = (const float*)d_in[7];
  const float* Wv = (const float*)d_in[8];
  const float* bv = (const float*)d_in[9];
  const float* Wo = (const float*)d_in[10];
  const float* bo = (const float*)d_in[11];

  float* out  = (float*)d_out;
  float* attn = out + (size_t)Bn * SQn * Hn;

  char* ws = (char*)d_ws;
  unsigned short* Qb = (unsigned short*)ws;
  unsigned short* Kb = Qb + (size_t)Bn * SQn * Hn;
  unsigned short* Vt = Kb + (size_t)Bn * SKn * Hn;
  unsigned short* Ob = Vt + (size_t)Bn * SKn * Hn;
  unsigned* mbits = (unsigned*)(Ob + (size_t)Bn * SQn * Hn);     // 4 MiB
  ushort_t* Wb = (ushort_t*)(mbits + (size_t)Bn * SQn * (SKn / 32));  // 512 KiB
  // X bf16 scratch in the attn output region: written by prep, read by
  // proj3, then overwritten by fused_attn_kernel (stream-ordered, safe).
  ushort_t* Xb = (ushort_t*)attn;

  prep_kernel<<<1808, 256, 0, stream>>>(mask, Wq, Wk, Wv, Wo,
                                        query, key_, value,
                                        (ull_t*)mbits, Wb, Xb);
  proj3_kernel<<<dim3(256, 4, 3), 256, 0, stream>>>(
      Xb, Wb, bq, bk, bv, Qb, Kb, Vt);
  fused_attn_kernel<<<4096, 512, 0, stream>>>(Qb, Kb, Vt, mbits, attn, Ob);
  oproj_kernel<<<dim3(256, 4), 256, 0, stream>>>(Ob, Wb + 3 * 65536, bo, out);
}